// Round 1
// baseline (277.961 us; speedup 1.0000x reference)
//
#include <hip/hip_runtime.h>
#include <math.h>

// BettingLoss: B x T (T=6) float32 inputs:
//   d_in[0] = predicted_probs, d_in[1] = true_winners, d_in[2] = market_odds
// Outputs (float32 x 3): loss, batch_profit, num_bets
//
// ALPHA=1.1, COMMISSION=0.05, BET_PCT=0.02, payout_scale = 0.02*0.95

constexpr int T = 6;
constexpr int NBLK = 2048;
constexpr int NTHR = 256;

__global__ __launch_bounds__(NTHR) void betting_stage1(
    const float* __restrict__ probs,
    const float* __restrict__ winners,
    const float* __restrict__ odds,
    double* __restrict__ partials,   // [NBLK][4]: sum_bet_ep, sum_profit, sum_maxp, count
    int B)
{
    const float ALPHA = 1.1f;
    const float BET = 0.02f;
    const float KEEP = 0.95f;            // 1 - commission
    const float PS = BET * KEEP;         // payout_scale

    double s_ep = 0.0, s_profit = 0.0, s_maxp = 0.0;
    int cnt = 0;

    const int stride = gridDim.x * blockDim.x;
    for (int r = blockIdx.x * blockDim.x + threadIdx.x; r < B; r += stride) {
        const float2* P = (const float2*)probs + (size_t)r * 3;
        const float2* O = (const float2*)odds  + (size_t)r * 3;
        float2 p0 = P[0], p1 = P[1], p2 = P[2];
        float2 o0 = O[0], o1 = O[1], o2 = O[2];
        float p[T] = {p0.x, p0.y, p1.x, p1.y, p2.x, p2.y};
        float o[T] = {o0.x, o0.y, o1.x, o1.y, o2.x, o2.y};

        bool valid = false;
        float maxp = p[0];
        #pragma unroll
        for (int j = 0; j < T; ++j) {
            valid |= (o[j] > 0.0f);
            maxp = fmaxf(maxp, p[j]);
        }
        s_maxp += (double)maxp;

        if (valid) {
            // ep_j = (odds*ALPHA*probs - 1) * payout_scale; first-max argmax
            float best_ep = -INFINITY;
            int best = 0;
            #pragma unroll
            for (int j = 0; j < T; ++j) {
                float ep = (o[j] * ALPHA * p[j] - 1.0f) * PS;
                if (ep > best_ep) { best_ep = ep; best = j; }
            }
            if (best_ep > 0.0f) {
                s_ep += (double)best_ep;
                cnt += 1;
                float w = winners[(size_t)r * T + best];   // only the one scalar we need
                float ob = o[best];
                float profit = (w > 0.5f)
                    ? (ob * ALPHA * BET - BET) * KEEP
                    : -BET * KEEP;
                s_profit += (double)profit;
            }
        }
    }

    // wave(64) reduction
    #pragma unroll
    for (int off = 32; off > 0; off >>= 1) {
        s_ep     += __shfl_down(s_ep, off);
        s_profit += __shfl_down(s_profit, off);
        s_maxp   += __shfl_down(s_maxp, off);
        cnt      += __shfl_down(cnt, off);
    }

    __shared__ double sm_ep[NTHR / 64];
    __shared__ double sm_pr[NTHR / 64];
    __shared__ double sm_mx[NTHR / 64];
    __shared__ int    sm_ct[NTHR / 64];
    const int lane = threadIdx.x & 63;
    const int wid  = threadIdx.x >> 6;
    if (lane == 0) {
        sm_ep[wid] = s_ep; sm_pr[wid] = s_profit; sm_mx[wid] = s_maxp; sm_ct[wid] = cnt;
    }
    __syncthreads();
    if (threadIdx.x == 0) {
        double t_ep = 0.0, t_pr = 0.0, t_mx = 0.0; int t_ct = 0;
        #pragma unroll
        for (int i = 0; i < NTHR / 64; ++i) {
            t_ep += sm_ep[i]; t_pr += sm_pr[i]; t_mx += sm_mx[i]; t_ct += sm_ct[i];
        }
        double* slot = partials + (size_t)blockIdx.x * 4;
        slot[0] = t_ep; slot[1] = t_pr; slot[2] = t_mx; slot[3] = (double)t_ct;
    }
}

__global__ __launch_bounds__(NTHR) void betting_stage2(
    const double* __restrict__ partials, float* __restrict__ out, int nblk, int B)
{
    double s_ep = 0.0, s_pr = 0.0, s_mx = 0.0, s_ct = 0.0;
    for (int i = threadIdx.x; i < nblk; i += blockDim.x) {
        const double* slot = partials + (size_t)i * 4;
        s_ep += slot[0]; s_pr += slot[1]; s_mx += slot[2]; s_ct += slot[3];
    }
    #pragma unroll
    for (int off = 32; off > 0; off >>= 1) {
        s_ep += __shfl_down(s_ep, off);
        s_pr += __shfl_down(s_pr, off);
        s_mx += __shfl_down(s_mx, off);
        s_ct += __shfl_down(s_ct, off);
    }
    __shared__ double sm[4][NTHR / 64];
    const int lane = threadIdx.x & 63;
    const int wid  = threadIdx.x >> 6;
    if (lane == 0) { sm[0][wid] = s_ep; sm[1][wid] = s_pr; sm[2][wid] = s_mx; sm[3][wid] = s_ct; }
    __syncthreads();
    if (threadIdx.x == 0) {
        double ep = 0.0, pr = 0.0, mx = 0.0, ct = 0.0;
        #pragma unroll
        for (int i = 0; i < NTHR / 64; ++i) { ep += sm[0][i]; pr += sm[1][i]; mx += sm[2][i]; ct += sm[3][i]; }
        bool any_bet = ct > 0.0;
        double total = any_bet ? ep : (-(mx / (double)B) * 0.1);
        out[0] = (float)(-total / (double)B);
        out[1] = (float)pr;
        out[2] = (float)ct;
    }
}

extern "C" void kernel_launch(void* const* d_in, const int* in_sizes, int n_in,
                              void* d_out, int out_size, void* d_ws, size_t ws_size,
                              hipStream_t stream) {
    const float* probs   = (const float*)d_in[0];
    const float* winners = (const float*)d_in[1];
    const float* odds    = (const float*)d_in[2];
    float* out = (float*)d_out;
    const int B = in_sizes[0] / T;

    double* partials = (double*)d_ws;   // NBLK * 4 doubles = 64 KiB; every slot written each call

    betting_stage1<<<NBLK, NTHR, 0, stream>>>(probs, winners, odds, partials, B);
    betting_stage2<<<1, NTHR, 0, stream>>>(partials, out, NBLK, B);
}